// Round 4
// baseline (1116.073 us; speedup 1.0000x reference)
//
#include <hip/hip_runtime.h>

#define N_NODES 100000
#define N_EDGES 3200000
#define FIN 512
#define FH 16
#define FC 40
#define NB_N ((N_NODES + 255) / 256)    // 391
#define BKT_SZ 128                      // nodes per dst bucket
#define NBKT ((N_NODES + BKT_SZ - 1) / BKT_SZ)  // 782
#define NBLK_P 256                      // partition blocks
#define CHUNK (N_EDGES / NBLK_P)        // 12500
#define ACC_STRIDE 17                   // 17 coprime 32 -> LDS banks spread

// ---- kA1: per-block bucket histogram (LDS atomics only) ----

__global__ __launch_bounds__(256) void kA1(const int* __restrict__ dst,
                                           int* __restrict__ H) {
  __shared__ int h[NBKT];
  int t = threadIdx.x;
  for (int i = t; i < NBKT; i += 256) h[i] = 0;
  __syncthreads();
  const int4* d4 = (const int4*)(dst + blockIdx.x * CHUNK);
  for (int i = t; i < CHUNK / 4; i += 256) {
    int4 v = d4[i];
    atomicAdd(&h[v.x >> 7], 1);
    atomicAdd(&h[v.y >> 7], 1);
    atomicAdd(&h[v.z >> 7], 1);
    atomicAdd(&h[v.w >> 7], 1);
  }
  __syncthreads();
  for (int i = t; i < NBKT; i += 256) H[blockIdx.x * NBKT + i] = h[i];
}

// ---- kA2: per-bucket exclusive scan over partition blocks; totals Tt ----

__global__ __launch_bounds__(256) void kA2(const int* __restrict__ H,
                                           int* __restrict__ P,
                                           int* __restrict__ Tt) {
  __shared__ int s[256];
  int t = threadIdx.x, b = blockIdx.x;
  int v = H[t * NBKT + b];
  s[t] = v;
  __syncthreads();
  for (int d = 1; d < 256; d <<= 1) {
    int x = (t >= d) ? s[t - d] : 0;
    __syncthreads();
    s[t] += x;
    __syncthreads();
  }
  P[t * NBKT + b] = s[t] - v;
  if (t == 255) Tt[b] = s[t];
}

// ---- kA3s: exclusive scan of bucket totals -> Base ----

__global__ __launch_bounds__(1024) void kA3s(const int* __restrict__ Tt,
                                             int* __restrict__ Base) {
  __shared__ int s[1024];
  int t = threadIdx.x;
  int v = (t < NBKT) ? Tt[t] : 0;
  s[t] = v;
  __syncthreads();
  for (int d = 1; d < 1024; d <<= 1) {
    int x = (t >= d) ? s[t - d] : 0;
    __syncthreads();
    s[t] += x;
    __syncthreads();
  }
  if (t < NBKT) Base[t] = s[t] - v;
}

// ---- kA3: place edges bucket-grouped; packed src | dlocal<<17 ----

__global__ __launch_bounds__(256) void kA3(const int* __restrict__ ei,
                                           const int* __restrict__ Base,
                                           const int* __restrict__ P,
                                           int* __restrict__ stage) {
  __shared__ int cur[NBKT];
  int t = threadIdx.x, blk = blockIdx.x;
  for (int i = t; i < NBKT; i += 256) cur[i] = Base[i] + P[blk * NBKT + i];
  __syncthreads();
  int base = blk * CHUNK;
  const int4* s4 = (const int4*)(ei + base);
  const int4* d4 = (const int4*)(ei + N_EDGES + base);
  for (int i = t; i < CHUNK / 4; i += 256) {
    int4 sv = s4[i], dv = d4[i];
    int slot;
    slot = atomicAdd(&cur[dv.x >> 7], 1); stage[slot] = sv.x | ((dv.x & 127) << 17);
    slot = atomicAdd(&cur[dv.y >> 7], 1); stage[slot] = sv.y | ((dv.y & 127) << 17);
    slot = atomicAdd(&cur[dv.z >> 7], 1); stage[slot] = sv.z | ((dv.z & 127) << 17);
    slot = atomicAdd(&cur[dv.w >> 7], 1); stage[slot] = sv.w | ((dv.w & 127) << 17);
  }
}

// ---- kC: per-bucket degree histogram -> dinv ----

__global__ __launch_bounds__(256) void kC(const int* __restrict__ stage,
                                          const int* __restrict__ Base,
                                          const int* __restrict__ Tt,
                                          float* __restrict__ dinv) {
  __shared__ int h[BKT_SZ];
  int t = threadIdx.x, b = blockIdx.x;
  if (t < BKT_SZ) h[t] = 0;
  __syncthreads();
  int base = Base[b], cnt = Tt[b];
  for (int i = t; i < cnt; i += 256) atomicAdd(&h[(stage[base + i] >> 17) & 127], 1);
  __syncthreads();
  int node = b * BKT_SZ + t;
  if (t < BKT_SZ && node < N_NODES) dinv[node] = rsqrtf((float)(h[t] + 1));
}

// ---------------- layer 1 GEMM: p1 = dinv * (x @ W1) ----------------

__global__ __launch_bounds__(256) void k_gemm1(const float* __restrict__ x,
                                               const float* __restrict__ W1,
                                               const float* __restrict__ dinv,
                                               float* __restrict__ p1) {
  __shared__ float xs[256 * 36];
  const int t = threadIdx.x;
  const int row0 = blockIdx.x * 256;
  const int row = row0 + t;
  float acc[FH];
#pragma unroll
  for (int c = 0; c < FH; c++) acc[c] = 0.0f;

  for (int kc = 0; kc < FIN; kc += 32) {
    float4 ld[8];
#pragma unroll
    for (int i = 0; i < 8; i++) {
      int idx = t + 256 * i;
      int r = idx >> 3, c4 = idx & 7;
      int gr = row0 + r;
      ld[i] = (gr < N_NODES)
                  ? *(const float4*)(x + (size_t)gr * FIN + kc + c4 * 4)
                  : make_float4(0.f, 0.f, 0.f, 0.f);
    }
    __syncthreads();
#pragma unroll
    for (int i = 0; i < 8; i++) {
      int idx = t + 256 * i;
      int r = idx >> 3, c4 = idx & 7;
      *(float4*)(&xs[r * 36 + c4 * 4]) = ld[i];
    }
    __syncthreads();
    float4 xr[8];
#pragma unroll
    for (int q = 0; q < 8; q++) xr[q] = *(const float4*)(&xs[t * 36 + q * 4]);
    const float4* w4 = (const float4*)(W1 + (size_t)kc * FH);  // wave-uniform
#pragma unroll
    for (int k = 0; k < 32; k++) {
      float xv = ((const float*)xr)[k];
      float4 wa = w4[k * 4 + 0], wb = w4[k * 4 + 1];
      float4 wc = w4[k * 4 + 2], wd = w4[k * 4 + 3];
      acc[0] = fmaf(xv, wa.x, acc[0]);   acc[1] = fmaf(xv, wa.y, acc[1]);
      acc[2] = fmaf(xv, wa.z, acc[2]);   acc[3] = fmaf(xv, wa.w, acc[3]);
      acc[4] = fmaf(xv, wb.x, acc[4]);   acc[5] = fmaf(xv, wb.y, acc[5]);
      acc[6] = fmaf(xv, wb.z, acc[6]);   acc[7] = fmaf(xv, wb.w, acc[7]);
      acc[8] = fmaf(xv, wc.x, acc[8]);   acc[9] = fmaf(xv, wc.y, acc[9]);
      acc[10] = fmaf(xv, wc.z, acc[10]); acc[11] = fmaf(xv, wc.w, acc[11]);
      acc[12] = fmaf(xv, wd.x, acc[12]); acc[13] = fmaf(xv, wd.y, acc[13]);
      acc[14] = fmaf(xv, wd.z, acc[14]); acc[15] = fmaf(xv, wd.w, acc[15]);
    }
  }

  if (row < N_NODES) {
    float dv = dinv[row];
#pragma unroll
    for (int c = 0; c < FH; c++) acc[c] *= dv;
#pragma unroll
    for (int q = 0; q < 4; q++)
      *(float4*)(p1 + (size_t)row * FH + q * 4) = ((const float4*)acc)[q];
  }
}

// ---- kG1: per-bucket LDS scatter-accumulate; q = dinv*relu(dinv*(acc+self)+b1)

__global__ __launch_bounds__(256) void kG1(const int* __restrict__ stage,
                                           const int* __restrict__ Base,
                                           const int* __restrict__ Tt,
                                           const float* __restrict__ p1,
                                           const float* __restrict__ dinv,
                                           const float* __restrict__ b1,
                                           float* __restrict__ q) {
  __shared__ float acc[BKT_SZ * ACC_STRIDE];  // 8704 B
  int t = threadIdx.x, b = blockIdx.x;
  for (int i = t; i < BKT_SZ * ACC_STRIDE; i += 256) acc[i] = 0.f;
  __syncthreads();
  int base = Base[b], cnt = Tt[b];
  int comp = t & 3;
  for (int i = (t >> 2); i < cnt; i += 64) {
    int pk = stage[base + i];
    int src = pk & 0x1FFFF;
    int dl = (pk >> 17) & 127;
    float4 v = *(const float4*)(p1 + (size_t)src * FH + comp * 4);
    float* a = &acc[dl * ACC_STRIDE + comp * 4];
    atomicAdd(a + 0, v.x);
    atomicAdd(a + 1, v.y);
    atomicAdd(a + 2, v.z);
    atomicAdd(a + 3, v.w);
  }
  __syncthreads();
  for (int idx = t; idx < BKT_SZ * 4; idx += 256) {
    int dl = idx >> 2, c = idx & 3;
    int node = b * BKT_SZ + dl;
    if (node >= N_NODES) continue;
    float dv = dinv[node];
    float4 sv = *(const float4*)(p1 + (size_t)node * FH + c * 4);  // self-loop
    float4 bb = *(const float4*)(b1 + c * 4);
    const float* a = &acc[dl * ACC_STRIDE + c * 4];
    float4 r;
    r.x = fmaxf(fmaf(a[0] + sv.x, dv, bb.x), 0.f) * dv;
    r.y = fmaxf(fmaf(a[1] + sv.y, dv, bb.y), 0.f) * dv;
    r.z = fmaxf(fmaf(a[2] + sv.z, dv, bb.z), 0.f) * dv;
    r.w = fmaxf(fmaf(a[3] + sv.w, dv, bb.w), 0.f) * dv;
    *(float4*)(q + (size_t)node * FH + c * 4) = r;
  }
}

// ---- kG2: per-bucket LDS scatter-accumulate + W2 matvec + log_softmax ----

__global__ __launch_bounds__(256) void kG2(const int* __restrict__ stage,
                                           const int* __restrict__ Base,
                                           const int* __restrict__ Tt,
                                           const float* __restrict__ q,
                                           const float* __restrict__ dinv,
                                           const float* __restrict__ W2,
                                           const float* __restrict__ b2,
                                           float* __restrict__ out) {
  __shared__ float acc[BKT_SZ * ACC_STRIDE];
  int t = threadIdx.x, b = blockIdx.x;
  for (int i = t; i < BKT_SZ * ACC_STRIDE; i += 256) acc[i] = 0.f;
  __syncthreads();
  int base = Base[b], cnt = Tt[b];
  int comp = t & 3;
  for (int i = (t >> 2); i < cnt; i += 64) {
    int pk = stage[base + i];
    int src = pk & 0x1FFFF;
    int dl = (pk >> 17) & 127;
    float4 v = *(const float4*)(q + (size_t)src * FH + comp * 4);
    float* a = &acc[dl * ACC_STRIDE + comp * 4];
    atomicAdd(a + 0, v.x);
    atomicAdd(a + 1, v.y);
    atomicAdd(a + 2, v.z);
    atomicAdd(a + 3, v.w);
  }
  __syncthreads();
  // fold self-loop into acc (coalesced float4 reads)
  for (int idx = t; idx < BKT_SZ * 4; idx += 256) {
    int dl = idx >> 2, c = idx & 3;
    int node = b * BKT_SZ + dl;
    if (node < N_NODES) {
      float4 sv = *(const float4*)(q + (size_t)node * FH + c * 4);
      float* a = &acc[dl * ACC_STRIDE + c * 4];
      a[0] += sv.x; a[1] += sv.y; a[2] += sv.z; a[3] += sv.w;
    }
  }
  __syncthreads();
  // lane = output class (reuses W2 column regs across all nodes of the bucket)
  int lane = t & 63, wv = t >> 6;
  float w2c[FH];
#pragma unroll
  for (int k = 0; k < FH; k++) w2c[k] = 0.f;
  float bc = 0.f;
  if (lane < FC) {
#pragma unroll
    for (int k = 0; k < FH; k++) w2c[k] = W2[k * FC + lane];
    bc = b2[lane];
  }
  for (int dl = wv; dl < BKT_SZ; dl += 4) {
    int node = b * BKT_SZ + dl;
    if (node >= N_NODES) continue;  // uniform per wave
    float dv = dinv[node];
    const float* ar = &acc[dl * ACC_STRIDE];
    float z = bc;
#pragma unroll
    for (int k = 0; k < FH; k++) z = fmaf(ar[k] * dv, w2c[k], z);  // LDS broadcast
    float zz = (lane < FC) ? z : -1e30f;
    float mx = zz;
#pragma unroll
    for (int d = 1; d < 64; d <<= 1) mx = fmaxf(mx, __shfl_xor(mx, d));
    float ex = (lane < FC) ? __expf(zz - mx) : 0.f;
#pragma unroll
    for (int d = 1; d < 64; d <<= 1) ex += __shfl_xor(ex, d);
    float l = __logf(ex) + mx;
    if (lane < FC) out[(size_t)node * FC + lane] = zz - l;
  }
}

// ---------------- launch ----------------

extern "C" void kernel_launch(void* const* d_in, const int* in_sizes, int n_in,
                              void* d_out, int out_size, void* d_ws, size_t ws_size,
                              hipStream_t stream) {
  const float* x  = (const float*)d_in[0];
  const int*   ei = (const int*)d_in[1];  // [2, E] int32
  const float* W1 = (const float*)d_in[2];
  const float* b1 = (const float*)d_in[3];
  const float* W2 = (const float*)d_in[4];
  const float* b2 = (const float*)d_in[5];
  float* out = (float*)d_out;

  // workspace (ints): H | P | Tt | Base | stage | dinv | p1 | q  (~28.2 MB)
  int* wsi   = (int*)d_ws;
  int* H     = wsi;                  // 256*782 = 200192
  int* P     = H + 200192;           // 200192
  int* Tt    = P + 200192;           // 800
  int* Base  = Tt + 800;             // 800
  int* stage = Base + 800;           // 3200000
  float* dinv = (float*)(stage + 3200000);  // 100352
  float* p1  = dinv + 100352;        // 1600000
  float* q   = p1 + 1600000;         // 1600000

  kA1 <<<NBLK_P, 256,  0, stream>>>(ei + N_EDGES, H);
  kA2 <<<NBKT,   256,  0, stream>>>(H, P, Tt);
  kA3s<<<1,      1024, 0, stream>>>(Tt, Base);
  kA3 <<<NBLK_P, 256,  0, stream>>>(ei, Base, P, stage);
  kC  <<<NBKT,   256,  0, stream>>>(stage, Base, Tt, dinv);
  k_gemm1<<<NB_N, 256, 0, stream>>>(x, W1, dinv, p1);
  kG1 <<<NBKT,   256,  0, stream>>>(stage, Base, Tt, p1, dinv, b1, q);
  kG2 <<<NBKT,   256,  0, stream>>>(stage, Base, Tt, q, dinv, W2, b2, out);
}

// Round 5
// 556.642 us; speedup vs baseline: 2.0050x; 2.0050x over previous
//
#include <hip/hip_runtime.h>

#define N_NODES 100000
#define N_EDGES 3200000
#define FIN 512
#define FH 16
#define FC 40
#define NB_N ((N_NODES + 255) / 256)   // 391
#define NBKT 391                        // dst buckets: dst>>8, 256 nodes each
#define NBLK_P 256                      // partition blocks
#define CHUNK (N_EDGES / NBLK_P)        // 12500 exactly

// ---- kA1: per-block bucket histogram (no global atomics) ----

__global__ __launch_bounds__(256) void kA1(const int* __restrict__ dst,
                                           int* __restrict__ H) {
  __shared__ int h[NBKT];
  int t = threadIdx.x;
  for (int i = t; i < NBKT; i += 256) h[i] = 0;
  __syncthreads();
  const int4* d4 = (const int4*)(dst + blockIdx.x * CHUNK);
  for (int i = t; i < CHUNK / 4; i += 256) {
    int4 v = d4[i];
    atomicAdd(&h[v.x >> 8], 1);
    atomicAdd(&h[v.y >> 8], 1);
    atomicAdd(&h[v.z >> 8], 1);
    atomicAdd(&h[v.w >> 8], 1);
  }
  __syncthreads();
  for (int i = t; i < NBKT; i += 256) H[blockIdx.x * NBKT + i] = h[i];
}

// ---- kA2: per-bucket column exclusive scan over blocks; totals T ----

__global__ __launch_bounds__(256) void kA2(const int* __restrict__ H,
                                           int* __restrict__ P,
                                           int* __restrict__ T) {
  __shared__ int s[256];
  int t = threadIdx.x, b = blockIdx.x;
  int v = H[t * NBKT + b];
  s[t] = v;
  __syncthreads();
  for (int d = 1; d < 256; d <<= 1) {
    int x = (t >= d) ? s[t - d] : 0;
    __syncthreads();
    s[t] += x;
    __syncthreads();
  }
  P[t * NBKT + b] = s[t] - v;  // exclusive sum of blocks < t for bucket b
  if (t == 255) T[b] = s[t];
}

// ---- kA3s: exclusive scan of bucket totals -> Base ----

__global__ __launch_bounds__(512) void kA3s(const int* __restrict__ T,
                                            int* __restrict__ Base,
                                            int* __restrict__ off) {
  __shared__ int s[512];
  int t = threadIdx.x;
  int v = (t < NBKT) ? T[t] : 0;
  s[t] = v;
  __syncthreads();
  for (int d = 1; d < 512; d <<= 1) {
    int x = (t >= d) ? s[t - d] : 0;
    __syncthreads();
    s[t] += x;
    __syncthreads();
  }
  if (t < NBKT) Base[t] = s[t] - v;
  if (t == 0) off[N_NODES] = N_EDGES;
}

// ---- kA3: place edges into bucket-grouped staging (LDS cursors) ----

__global__ __launch_bounds__(256) void kA3(const int* __restrict__ ei,
                                           const int* __restrict__ Base,
                                           const int* __restrict__ P,
                                           int* __restrict__ stage) {
  __shared__ int cur[NBKT];
  int t = threadIdx.x, blk = blockIdx.x;
  for (int i = t; i < NBKT; i += 256) cur[i] = Base[i] + P[blk * NBKT + i];
  __syncthreads();
  int base = blk * CHUNK;
  const int4* s4 = (const int4*)(ei + base);
  const int4* d4 = (const int4*)(ei + N_EDGES + base);
  for (int i = t; i < CHUNK / 4; i += 256) {
    int4 sv = s4[i], dv = d4[i];
    int slot;
    slot = atomicAdd(&cur[dv.x >> 8], 1); stage[slot] = sv.x | ((dv.x & 255) << 17);
    slot = atomicAdd(&cur[dv.y >> 8], 1); stage[slot] = sv.y | ((dv.y & 255) << 17);
    slot = atomicAdd(&cur[dv.z >> 8], 1); stage[slot] = sv.z | ((dv.z & 255) << 17);
    slot = atomicAdd(&cur[dv.w >> 8], 1); stage[slot] = sv.w | ((dv.w & 255) << 17);
  }
}

// ---- kB: per-bucket CSR finalize: off[], dinv[], csr[] (all block-local) ----

__global__ __launch_bounds__(256) void kB(const int* __restrict__ stage,
                                          const int* __restrict__ Base,
                                          const int* __restrict__ T,
                                          int* __restrict__ off,
                                          int* __restrict__ csr,
                                          float* __restrict__ dinv) {
  __shared__ int hist[256], cursor[256], sc[256];
  int t = threadIdx.x, b = blockIdx.x;
  int base = Base[b], cnt = T[b];
  hist[t] = 0;
  __syncthreads();
  for (int i = t; i < cnt; i += 256) atomicAdd(&hist[stage[base + i] >> 17], 1);
  __syncthreads();
  int c = hist[t];
  sc[t] = c;
  __syncthreads();
  for (int d = 1; d < 256; d <<= 1) {
    int x = (t >= d) ? sc[t - d] : 0;
    __syncthreads();
    sc[t] += x;
    __syncthreads();
  }
  int excl = sc[t] - c;
  int node = b * 256 + t;
  if (node < N_NODES) {
    off[node] = base + excl;
    dinv[node] = rsqrtf((float)(c + 1));  // +1 self-loop
  }
  cursor[t] = excl;
  __syncthreads();
  for (int i = t; i < cnt; i += 256) {
    int pk = stage[base + i];
    int slot = atomicAdd(&cursor[pk >> 17], 1);  // LDS atomic
    csr[base + slot] = pk & 0x1FFFF;
  }
}

// ---------------- layer 1 GEMM: p1 = dinv * (x @ W1) ----------------

__global__ __launch_bounds__(256) void k_gemm1(const float* __restrict__ x,
                                               const float* __restrict__ W1,
                                               const float* __restrict__ dinv,
                                               float* __restrict__ p1) {
  __shared__ float xs[256 * 36];
  const int t = threadIdx.x;
  const int row0 = blockIdx.x * 256;
  const int row = row0 + t;
  float acc[FH];
#pragma unroll
  for (int c = 0; c < FH; c++) acc[c] = 0.0f;

  for (int kc = 0; kc < FIN; kc += 32) {
    float4 ld[8];
#pragma unroll
    for (int i = 0; i < 8; i++) {
      int idx = t + 256 * i;
      int r = idx >> 3, c4 = idx & 7;
      int gr = row0 + r;
      ld[i] = (gr < N_NODES)
                  ? *(const float4*)(x + (size_t)gr * FIN + kc + c4 * 4)
                  : make_float4(0.f, 0.f, 0.f, 0.f);
    }
    __syncthreads();
#pragma unroll
    for (int i = 0; i < 8; i++) {
      int idx = t + 256 * i;
      int r = idx >> 3, c4 = idx & 7;
      *(float4*)(&xs[r * 36 + c4 * 4]) = ld[i];
    }
    __syncthreads();
    float4 xr[8];
#pragma unroll
    for (int q = 0; q < 8; q++) xr[q] = *(const float4*)(&xs[t * 36 + q * 4]);
    const float4* w4 = (const float4*)(W1 + (size_t)kc * FH);  // wave-uniform
#pragma unroll
    for (int k = 0; k < 32; k++) {
      float xv = ((const float*)xr)[k];
      float4 wa = w4[k * 4 + 0], wb = w4[k * 4 + 1];
      float4 wc = w4[k * 4 + 2], wd = w4[k * 4 + 3];
      acc[0] = fmaf(xv, wa.x, acc[0]);   acc[1] = fmaf(xv, wa.y, acc[1]);
      acc[2] = fmaf(xv, wa.z, acc[2]);   acc[3] = fmaf(xv, wa.w, acc[3]);
      acc[4] = fmaf(xv, wb.x, acc[4]);   acc[5] = fmaf(xv, wb.y, acc[5]);
      acc[6] = fmaf(xv, wb.z, acc[6]);   acc[7] = fmaf(xv, wb.w, acc[7]);
      acc[8] = fmaf(xv, wc.x, acc[8]);   acc[9] = fmaf(xv, wc.y, acc[9]);
      acc[10] = fmaf(xv, wc.z, acc[10]); acc[11] = fmaf(xv, wc.w, acc[11]);
      acc[12] = fmaf(xv, wd.x, acc[12]); acc[13] = fmaf(xv, wd.y, acc[13]);
      acc[14] = fmaf(xv, wd.z, acc[14]); acc[15] = fmaf(xv, wd.w, acc[15]);
    }
  }

  if (row < N_NODES) {
    float dv = dinv[row];
#pragma unroll
    for (int c = 0; c < FH; c++) acc[c] *= dv;
#pragma unroll
    for (int q = 0; q < 4; q++)
      *(float4*)(p1 + (size_t)row * FH + q * 4) = ((const float4*)acc)[q];
  }
}

// ---- gather layer 1: q = dinv * relu(dinv * (p1[self] + sum p1[src]) + b1) ----
// one wave per node; 32 edges per loop trip (two independent gather chains)

__global__ __launch_bounds__(256) void k_gather1(const int* __restrict__ off,
                                                 const int* __restrict__ csr,
                                                 const float* __restrict__ p1,
                                                 const float* __restrict__ dinv,
                                                 const float* __restrict__ b1,
                                                 float* __restrict__ q) {
  int lane = threadIdx.x & 63;
  int node = blockIdx.x * 4 + (threadIdx.x >> 6);
  int start = off[node];
  int end = off[node + 1];
  int slot = lane >> 2, comp = lane & 3;
  float4 acc = make_float4(0.f, 0.f, 0.f, 0.f);
  if (slot == 0)  // self-loop
    acc = *(const float4*)(p1 + (size_t)node * FH + comp * 4);
  for (int base = start; base < end; base += 32) {
    int e0 = base + slot, e1 = e0 + 16;
    int s0 = (e0 < end) ? csr[e0] : -1;
    int s1 = (e1 < end) ? csr[e1] : -1;
    if (s0 >= 0) {
      float4 v = *(const float4*)(p1 + (size_t)s0 * FH + comp * 4);
      acc.x += v.x; acc.y += v.y; acc.z += v.z; acc.w += v.w;
    }
    if (s1 >= 0) {
      float4 v = *(const float4*)(p1 + (size_t)s1 * FH + comp * 4);
      acc.x += v.x; acc.y += v.y; acc.z += v.z; acc.w += v.w;
    }
  }
#pragma unroll
  for (int m = 4; m <= 32; m <<= 1) {
    acc.x += __shfl_xor(acc.x, m);
    acc.y += __shfl_xor(acc.y, m);
    acc.z += __shfl_xor(acc.z, m);
    acc.w += __shfl_xor(acc.w, m);
  }
  float dv = dinv[node];
  if (lane < 4) {  // comp == lane
    float4 bb = *(const float4*)(b1 + lane * 4);
    float4 r;
    r.x = fmaxf(fmaf(acc.x, dv, bb.x), 0.f) * dv;
    r.y = fmaxf(fmaf(acc.y, dv, bb.y), 0.f) * dv;
    r.z = fmaxf(fmaf(acc.z, dv, bb.z), 0.f) * dv;
    r.w = fmaxf(fmaf(acc.w, dv, bb.w), 0.f) * dv;
    *(float4*)(q + (size_t)node * FH + lane * 4) = r;
  }
}

// ---- gather layer 2 + W2 matvec + log_softmax, fused ----

__global__ __launch_bounds__(256) void k_gather2(const int* __restrict__ off,
                                                 const int* __restrict__ csr,
                                                 const float* __restrict__ q,
                                                 const float* __restrict__ dinv,
                                                 const float* __restrict__ W2,
                                                 const float* __restrict__ b2,
                                                 float* __restrict__ out) {
  int lane = threadIdx.x & 63;
  int node = blockIdx.x * 4 + (threadIdx.x >> 6);
  int start = off[node];
  int end = off[node + 1];
  int slot = lane >> 2, comp = lane & 3;
  float4 acc = make_float4(0.f, 0.f, 0.f, 0.f);
  if (slot == 0)  // self-loop
    acc = *(const float4*)(q + (size_t)node * FH + comp * 4);
  for (int base = start; base < end; base += 32) {
    int e0 = base + slot, e1 = e0 + 16;
    int s0 = (e0 < end) ? csr[e0] : -1;
    int s1 = (e1 < end) ? csr[e1] : -1;
    if (s0 >= 0) {
      float4 v = *(const float4*)(q + (size_t)s0 * FH + comp * 4);
      acc.x += v.x; acc.y += v.y; acc.z += v.z; acc.w += v.w;
    }
    if (s1 >= 0) {
      float4 v = *(const float4*)(q + (size_t)s1 * FH + comp * 4);
      acc.x += v.x; acc.y += v.y; acc.z += v.z; acc.w += v.w;
    }
  }
#pragma unroll
  for (int m = 4; m <= 32; m <<= 1) {
    acc.x += __shfl_xor(acc.x, m);
    acc.y += __shfl_xor(acc.y, m);
    acc.z += __shfl_xor(acc.z, m);
    acc.w += __shfl_xor(acc.w, m);
  }
  float dv = dinv[node];
  acc.x *= dv; acc.y *= dv; acc.z *= dv; acc.w *= dv;
  float t16[16];
  t16[comp * 4 + 0] = acc.x; t16[comp * 4 + 1] = acc.y;
  t16[comp * 4 + 2] = acc.z; t16[comp * 4 + 3] = acc.w;
#pragma unroll
  for (int m = 1; m <= 3; m++) {
    int oc = comp ^ m;
    t16[oc * 4 + 0] = __shfl_xor(acc.x, m);
    t16[oc * 4 + 1] = __shfl_xor(acc.y, m);
    t16[oc * 4 + 2] = __shfl_xor(acc.z, m);
    t16[oc * 4 + 3] = __shfl_xor(acc.w, m);
  }
  float z = -1e30f;
  if (lane < FC) {
    z = b2[lane];
#pragma unroll
    for (int k = 0; k < FH; k++) z = fmaf(t16[k], W2[k * FC + lane], z);
  }
  float mx = z;
#pragma unroll
  for (int d = 1; d < 64; d <<= 1) mx = fmaxf(mx, __shfl_xor(mx, d));
  float ex = (lane < FC) ? __expf(z - mx) : 0.f;
#pragma unroll
  for (int d = 1; d < 64; d <<= 1) ex += __shfl_xor(ex, d);
  float l = __logf(ex) + mx;
  if (lane < FC) out[(size_t)node * FC + lane] = z - l;
}

// ---------------- launch ----------------

extern "C" void kernel_launch(void* const* d_in, const int* in_sizes, int n_in,
                              void* d_out, int out_size, void* d_ws, size_t ws_size,
                              hipStream_t stream) {
  const float* x  = (const float*)d_in[0];
  const int*   ei = (const int*)d_in[1];  // [2, E] int32
  const float* W1 = (const float*)d_in[2];
  const float* b1 = (const float*)d_in[3];
  const float* W2 = (const float*)d_in[4];
  const float* b2 = (const float*)d_in[5];
  float* out = (float*)d_out;

  // workspace (ints): H | P | T | Base | off | csr | stage(->p1|q) | dinv
  int* wsi  = (int*)d_ws;
  int* H    = wsi;                  // 100096
  int* P    = H + 100096;           // 100096
  int* T    = P + 100096;           // 512
  int* Base = T + 512;              // 512
  int* off  = Base + 512;           // 100352
  int* csr  = off + 100352;         // 3200000
  int* stage = csr + 3200000;       // 3200000
  float* dinv = (float*)(stage + 3200000);  // 100352
  float* p1 = (float*)stage;        // stage dead after kB
  float* q  = p1 + 1600000;

  kA1 <<<NBLK_P, 256, 0, stream>>>(ei + N_EDGES, H);
  kA2 <<<NBKT,   256, 0, stream>>>(H, P, T);
  kA3s<<<1,      512, 0, stream>>>(T, Base, off);
  kA3 <<<NBLK_P, 256, 0, stream>>>(ei, Base, P, stage);
  kB  <<<NBKT,   256, 0, stream>>>(stage, Base, T, off, csr, dinv);
  k_gemm1  <<<NB_N, 256, 0, stream>>>(x, W1, dinv, p1);
  k_gather1<<<N_NODES / 4, 256, 0, stream>>>(off, csr, p1, dinv, b1, q);
  k_gather2<<<N_NODES / 4, 256, 0, stream>>>(off, csr, q, dinv, W2, b2, out);
}